// Round 1
// baseline (207.993 us; speedup 1.0000x reference)
//
#include <hip/hip_runtime.h>

// Problem constants (match reference)
#define B 16
#define C 128
#define N 16384
#define K 64

// Tiling
#define CT 32          // channels per block
#define NB 2048        // points per block
#define LDS_STRIDE 33  // K-row stride in LDS (pad: bank = (k+c)%32, spreads random k)

#define ENC_NEG_INF 0x007FFFFFu  // enc(-inf)

__device__ __forceinline__ unsigned enc(float f) {
    unsigned u = __float_as_uint(f);
    return (u & 0x80000000u) ? ~u : (u | 0x80000000u);
}
__device__ __forceinline__ float dec(unsigned u) {
    unsigned v = (u & 0x80000000u) ? (u & 0x7FFFFFFFu) : ~u;
    return __uint_as_float(v);
}

__global__ void seg_init(unsigned* __restrict__ gseg) {
    int i = blockIdx.x * blockDim.x + threadIdx.x;
    if (i < B * K * C) gseg[i] = ENC_NEG_INF;
}

__global__ __launch_bounds__(256) void seg_scatter(const float* __restrict__ pf,
                                                   const int* __restrict__ ids,
                                                   unsigned* __restrict__ gseg) {
    __shared__ unsigned lds[K * LDS_STRIDE];
    const int tid = threadIdx.x;
    const int b  = blockIdx.z;
    const int c0 = blockIdx.y * CT;
    const int n0 = blockIdx.x * NB;

    for (int i = tid; i < K * LDS_STRIDE; i += 256) lds[i] = ENC_NEG_INF;

    // This thread's 8 points: two float4-groups at tid and tid+256 within the chunk.
    const int4* ids4 = reinterpret_cast<const int4*>(ids + b * N + n0);
    const int4 ka = ids4[tid];
    const int4 kb = ids4[tid + 256];
    __syncthreads();

    const float* base = pf + ((size_t)b * C + c0) * N + n0;
#pragma unroll 4
    for (int c = 0; c < CT; ++c) {
        const float4* src = reinterpret_cast<const float4*>(base + (size_t)c * N);
        float4 va = src[tid];
        float4 vb = src[tid + 256];
        atomicMax(&lds[ka.x * LDS_STRIDE + c], enc(va.x));
        atomicMax(&lds[ka.y * LDS_STRIDE + c], enc(va.y));
        atomicMax(&lds[ka.z * LDS_STRIDE + c], enc(va.z));
        atomicMax(&lds[ka.w * LDS_STRIDE + c], enc(va.w));
        atomicMax(&lds[kb.x * LDS_STRIDE + c], enc(vb.x));
        atomicMax(&lds[kb.y * LDS_STRIDE + c], enc(vb.y));
        atomicMax(&lds[kb.z * LDS_STRIDE + c], enc(vb.z));
        atomicMax(&lds[kb.w * LDS_STRIDE + c], enc(vb.w));
    }
    __syncthreads();

    // Merge block-local table into global table.
    for (int i = tid; i < K * CT; i += 256) {
        int k = i / CT, c = i % CT;
        unsigned v = lds[k * LDS_STRIDE + c];
        if (v != ENC_NEG_INF)
            atomicMax(&gseg[((size_t)(b * K + k)) * C + c0 + c], v);
    }
}

__global__ void seg_gather(const unsigned* __restrict__ gseg,
                           const int* __restrict__ common,
                           float* __restrict__ out) {
    int i = blockIdx.x * blockDim.x + threadIdx.x;  // over B*K*C
    if (i >= B * K * C) return;
    int c = i % C;
    int row = i / C;          // b*K + j
    int b = row / K;
    int cid = common[row];    // common cluster label for this output row
    out[i] = dec(gseg[((size_t)(b * K + cid)) * C + c]);
}

extern "C" void kernel_launch(void* const* d_in, const int* in_sizes, int n_in,
                              void* d_out, int out_size, void* d_ws, size_t ws_size,
                              hipStream_t stream) {
    const float* pf     = (const float*)d_in[0];   // (B, C, N) f32
    const int*   ids    = (const int*)d_in[1];     // (B, N) i32
    const int*   common = (const int*)d_in[2];     // (B, K) i32
    float* out = (float*)d_out;                    // (B*K, C) f32
    unsigned* gseg = (unsigned*)d_ws;              // B*K*C uints = 512 KB

    const int total = B * K * C;  // 131072
    seg_init<<<(total + 255) / 256, 256, 0, stream>>>(gseg);

    dim3 grid(N / NB, C / CT, B);  // (8, 4, 16) = 512 blocks
    seg_scatter<<<grid, 256, 0, stream>>>(pf, ids, gseg);

    seg_gather<<<(total + 255) / 256, 256, 0, stream>>>(gseg, common, out);
}

// Round 3
// 195.351 us; speedup vs baseline: 1.0647x; 1.0647x over previous
//
#include <hip/hip_runtime.h>

// Problem constants (match reference)
#define B 16
#define C 128
#define N 16384
#define K 64

// Tiling
#define CT 32            // channels per block
#define NCH 16           // n-chunks per cloud
#define NB (N / NCH)     // 1024 points per block
#define NCT (C / CT)     // 4 channel tiles
#define LDSS 33          // K-row stride in LDS (bank = (k+c)%32, spreads random k)

#define ENC_NEG_INF 0x007FFFFFu  // enc(-inf)

__device__ __forceinline__ unsigned enc(float f) {
    unsigned u = __float_as_uint(f);
    return (u & 0x80000000u) ? ~u : (u | 0x80000000u);
}
__device__ __forceinline__ float dec(unsigned u) {
    unsigned v = (u & 0x80000000u) ? (u & 0x7FFFFFFFu) : ~u;
    return __uint_as_float(v);
}

// Partial tables in ws: part[b][ct][chunk][k][cl]  (u32), 16*4*16*64*32*4B = 8 MB
__global__ __launch_bounds__(256) void seg_scatter(const float* __restrict__ pf,
                                                   const int* __restrict__ ids,
                                                   unsigned* __restrict__ part) {
    __shared__ unsigned lds[K * LDSS];
    const int tid   = threadIdx.x;
    const int chunk = blockIdx.x;
    const int ct    = blockIdx.y;
    const int b     = blockIdx.z;
    const int c0    = ct * CT;
    const int n0    = chunk * NB;

    for (int i = tid; i < K * LDSS; i += 256) lds[i] = ENC_NEG_INF;

    // 4 points per thread: one int4 of cluster ids, one float4 per channel.
    const int4 kk = reinterpret_cast<const int4*>(ids + b * N + n0)[tid];
    const int kx = kk.x * LDSS, ky = kk.y * LDSS, kz = kk.z * LDSS, kw = kk.w * LDSS;
    __syncthreads();

    const float* base = pf + ((size_t)b * C + c0) * N + n0;
    float4 cur = reinterpret_cast<const float4*>(base)[tid];
#pragma unroll
    for (int c = 0; c < CT; ++c) {
        float4 nxt = cur;
        if (c + 1 < CT)
            nxt = reinterpret_cast<const float4*>(base + (size_t)(c + 1) * N)[tid];
        atomicMax(&lds[kx + c], enc(cur.x));
        atomicMax(&lds[ky + c], enc(cur.y));
        atomicMax(&lds[kz + c], enc(cur.z));
        atomicMax(&lds[kw + c], enc(cur.w));
        cur = nxt;
    }
    __syncthreads();

    // Linear coalesced dump of the block-local table (no atomics).
    unsigned* dst = part + (((size_t)(b * NCT + ct) * NCH + chunk) * K) * CT;
    for (int i = tid; i < K * CT; i += 256) {
        int k = i >> 5, cl = i & 31;
        dst[i] = lds[k * LDSS + cl];
    }
}

// Reduce the NCH partials and gather common cluster labels, 4 channels/thread.
__global__ __launch_bounds__(256) void seg_reduce(const unsigned* __restrict__ part,
                                                  const int* __restrict__ common,
                                                  float* __restrict__ out) {
    const int i = blockIdx.x * blockDim.x + threadIdx.x;  // over B*K*C/4 = 32768
    if (i >= B * K * C / 4) return;
    const int c0  = (i & 31) * 4;         // channel of first element
    const int row = i >> 5;               // b*K + j
    const int cid = common[row];          // common cluster label
    const int b   = row >> 6;
    const int ct  = c0 >> 5, cl = c0 & 31;

    const unsigned* p = part + (((size_t)(b * NCT + ct) * NCH) * K + cid) * CT + cl;
    uint4 m = make_uint4(ENC_NEG_INF, ENC_NEG_INF, ENC_NEG_INF, ENC_NEG_INF);
#pragma unroll
    for (int ch = 0; ch < NCH; ++ch) {
        uint4 v = *reinterpret_cast<const uint4*>(p + (size_t)ch * K * CT);
        m.x = max(m.x, v.x); m.y = max(m.y, v.y);
        m.z = max(m.z, v.z); m.w = max(m.w, v.w);
    }
    float4 o = make_float4(dec(m.x), dec(m.y), dec(m.z), dec(m.w));
    reinterpret_cast<float4*>(out)[i] = o;
}

extern "C" void kernel_launch(void* const* d_in, const int* in_sizes, int n_in,
                              void* d_out, int out_size, void* d_ws, size_t ws_size,
                              hipStream_t stream) {
    const float* pf     = (const float*)d_in[0];   // (B, C, N) f32
    const int*   ids    = (const int*)d_in[1];     // (B, N) i32
    const int*   common = (const int*)d_in[2];     // (B, K) i32
    float* out = (float*)d_out;                    // (B*K, C) f32
    unsigned* part = (unsigned*)d_ws;              // 8 MB partial tables

    dim3 grid(NCH, NCT, B);  // (16, 4, 16) = 1024 blocks
    seg_scatter<<<grid, 256, 0, stream>>>(pf, ids, part);

    const int rtotal = B * K * C / 4;  // 32768
    seg_reduce<<<(rtotal + 255) / 256, 256, 0, stream>>>(part, common, out);
}